// Round 8
// baseline (143.249 us; speedup 1.0000x reference)
//
#include <hip/hip_runtime.h>

// SLAYER SNN forward, MI355X. Round 8.
// k0: fold conv1+pool1 (8x8 stride-4 taps) and conv2+pool2 weights once.
// k1: conv1+pool1, R7 version (e-split lane pairs, 6400 one-wave blocks).
// kf: FUSED scan1+conv2+scan2+dense. 64 blocks (one per batch-n) x 256 thr.
//     Pipelined 8 timesteps/round (13 rounds). s1 ring = k3's exact padded
//     660-float tile layout per t-slot so the conv2 body/FMA tree is verbatim
//     round-7 k3 (bit-exact). u2/s2 ring in LDS (132-stride). u1 prefetched
//     8-deep so HBM latency hides behind conv2/dense compute.
//     Removes: s1 global write-back, u2 global entirely, 2 launches + gaps.
// FP32; all per-output summation trees identical to round 7 (absmax 0.0).

#define DECAY 0.9048374180359595f   // exp(-1/10)

// ---------------- k0: fold weights ----------------
// wl1[(cin*8 + e)*32 + c*8 + f], e,f in 0..7  (512 floats)
// wl2[c2*68 + cin*16 + e*4 + f]               (544 floats incl. unused pads)
__global__ __launch_bounds__(128) void k0_fold(const float* __restrict__ w1,
        const float* __restrict__ w2, const float* __restrict__ wp1,
        const float* __restrict__ wp2, float* __restrict__ wl1,
        float* __restrict__ wl2) {
    const int tid = threadIdx.x;
    const float p1 = wp1[0], p2 = wp2[0];
    for (int idx = tid; idx < 512; idx += 128) {
        const int f = idx & 7, c = (idx >> 3) & 3, e = (idx >> 5) & 7, cin = idx >> 8;
        const int cc = c * 2 + cin;
        int alo = e - 3; if (alo < 0) alo = 0;
        int ahi = e;     if (ahi > 4) ahi = 4;
        int blo = f - 3; if (blo < 0) blo = 0;
        int bhi = f;     if (bhi > 4) bhi = 4;
        float s = 0.f;
        for (int a = alo; a <= ahi; ++a)
            for (int b = blo; b <= bhi; ++b)
                s += w1[cc * 25 + a * 5 + b];
        wl1[(cin * 8 + e) * 32 + c * 8 + f] = s * p1;
    }
    for (int idx = tid; idx < 512; idx += 128) {
        const int c2 = idx & 7, f = (idx >> 3) & 3, e = (idx >> 5) & 3, cin = idx >> 7;
        int alo = e - 1; if (alo < 0) alo = 0;
        int ahi = e;     if (ahi > 2) ahi = 2;
        int blo = f - 1; if (blo < 0) blo = 0;
        int bhi = f;     if (bhi > 2) bhi = 2;
        float s = 0.f;
        for (int aa = alo; aa <= ahi; ++aa)
            for (int bb = blo; bb <= bhi; ++bb)
                s += w2[((c2 * 4 + cin) * 3 + aa) * 3 + bb];
        wl2[c2 * 68 + cin * 16 + e * 4 + f] = s * p2;
    }
}

// ---------------- k1: conv1+pool1, 8x8-tap stride-4 (R7, unchanged) ----------------
__global__ __launch_bounds__(64) void k1(const float* __restrict__ x,
        const float* __restrict__ wg, float* __restrict__ u1) {
    __shared__ __align__(16) float xs[2 * 1296];   // 10.1 KB
    __shared__ __align__(16) float wl[512];        // 2 KB
    const int lane = threadIdx.x;
    const int frame = blockIdx.x;                  // = n*100 + t (x is n-major)
    const int n = frame / 100, t = frame % 100;

    *(float4*)(wl + 4 * lane)       = *(const float4*)(wg + 4 * lane);
    *(float4*)(wl + 256 + 4 * lane) = *(const float4*)(wg + 256 + 4 * lane);

    #pragma unroll
    for (int m0 = 0; m0 < 128; m0 += 64) {
        const int m = m0 + lane;
        if (m < 72) {
            const int cin = m / 36, rem = m % 36;
            const int rr = rem / 9, q4 = rem % 9;
            const int pr = (rr == 0) ? 0 : (rr == 1) ? 9 : (rr == 2) ? 26 : 35;
            *(float4*)(xs + cin * 1296 + pr * 36 + q4 * 4) = make_float4(0.f, 0.f, 0.f, 0.f);
        }
    }
    #pragma unroll
    for (int m0 = 0; m0 < 192; m0 += 64) {
        const int m = m0 + lane;
        if (m < 144) {
            const int cin = m / 72, rem = m % 72;
            const int side = rem & 1, pr = rem >> 1;
            *(float2*)(xs + cin * 1296 + pr * 36 + side * 34) = make_float2(0.f, 0.f);
        }
    }
    const float4* xg = (const float4*)(x + (size_t)frame * 2048);
    #pragma unroll
    for (int q = 0; q < 8; ++q) {
        const int m = q * 64 + lane;
        const float4 v = xg[m];
        const int li = 4 * m;
        const int cin = li >> 10, row = (li >> 5) & 31, col = li & 31;
        const int r = row + 2;
        const int pr = (r & 3) * 9 + (r >> 2);
        float* d = xs + cin * 1296 + pr * 36 + col + 2;
        *(float2*)(d)     = make_float2(v.x, v.y);
        *(float2*)(d + 2) = make_float2(v.z, v.w);
    }
    __syncthreads();

    const int cp = lane >> 5;
    const int i  = (lane >> 2) & 7;
    const int jh = (lane >> 1) & 1;
    const int eh = lane & 1;

    float acc[2][4] = {{0.f, 0.f, 0.f, 0.f}, {0.f, 0.f, 0.f, 0.f}};
    const float* tb = xs + (i + eh) * 36 + jh * 16;
    #pragma unroll
    for (int cin = 0; cin < 2; ++cin) {
        #pragma unroll
        for (int et = 0; et < 4; ++et) {
            const int ro = cin * 1296 + et * 9 * 36;
            float xr[20];
            #pragma unroll
            for (int b = 0; b < 5; ++b)
                *(float4*)(xr + 4 * b) = *(const float4*)(tb + ro + 4 * b);
            float wv[16];
            const float* wp = wl + (cin * 8 + eh * 4 + et) * 32 + cp * 16;
            #pragma unroll
            for (int q = 0; q < 4; ++q)
                *(float4*)(wv + 4 * q) = *(const float4*)(wp + 4 * q);
            #pragma unroll
            for (int cl = 0; cl < 2; ++cl) {
                #pragma unroll
                for (int jj = 0; jj < 4; ++jj) {
                    const int o = 4 * jj;
                    acc[cl][jj] += xr[o]*wv[cl*8]     + xr[o+1]*wv[cl*8+1]
                                 + xr[o+2]*wv[cl*8+2] + xr[o+3]*wv[cl*8+3]
                                 + xr[o+4]*wv[cl*8+4] + xr[o+5]*wv[cl*8+5]
                                 + xr[o+6]*wv[cl*8+6] + xr[o+7]*wv[cl*8+7];
                }
            }
        }
    }
    #pragma unroll
    for (int cl = 0; cl < 2; ++cl)
        #pragma unroll
        for (int jj = 0; jj < 4; ++jj)
            acc[cl][jj] += __shfl_xor(acc[cl][jj], 1);

    const float o0 = eh ? acc[1][0] : acc[0][0];
    const float o1 = eh ? acc[1][1] : acc[0][1];
    const float o2 = eh ? acc[1][2] : acc[0][2];
    const float o3 = eh ? acc[1][3] : acc[0][3];
    *(float4*)(u1 + (size_t)t * 16384 + n * 256 + (2 * cp + eh) * 64 + i * 8 + jh * 4) =
        make_float4(o0, o1, o2, o3);
}

// ---------------- kf: fused scan1 + conv2 + scan2 + dense ----------------
// grid 64 x 256, block = one batch index n. 8 t-steps per round, 13 rounds.
// ls1: 8 slots x k3's 660-float padded tile (cin*160 + perm-row*16 + col,
//      perm(r)=(r&1)*5+(r>>1), logical col C at phys C+4; halos stay zero).
// ls2: 8 slots x 132 (c2*16 + pos), u2 then s2 in place.
__global__ __launch_bounds__(256) void kf(const float* __restrict__ u1,
        const float* __restrict__ wl2g, const float* __restrict__ lw,
        float* __restrict__ out) {
    __shared__ __align__(16) float ls1[8 * 660];   // 21.1 KB
    __shared__ __align__(16) float ls2[8 * 132];   //  4.2 KB
    __shared__ __align__(16) float wl[544];
    const int tid = threadIdx.x, n = blockIdx.x;
    const int wave = tid >> 6, l64 = tid & 63;
    const int sub = tid >> 5, l = tid & 31;
    const float a = DECAY;

    // weights + ring zero (halos of ls1 must be 0; interior rewritten per round)
    if (tid < 136) *(float4*)(wl + 4 * tid) = *(const float4*)(wl2g + 4 * tid);
    for (int m = tid; m < 1320; m += 256)
        *(float4*)(ls1 + 4 * m) = make_float4(0.f, 0.f, 0.f, 0.f);

    // scan1: thread = neuron (c,row,col) = tid; LDS write offset in tile
    const int cs = tid >> 6, rowi = (tid >> 3) & 7, col = tid & 7;
    const int pr1 = (((rowi + 1) & 1) * 5) + ((rowi + 1) >> 1);
    const int woff = cs * 160 + pr1 * 16 + 4 + col;
    const float* up = u1 + n * 256 + tid;

    // conv2 thread mapping (verbatim k3)
    const int c2 = l >> 2, i2 = l & 3;
    const float* wb = wl + c2 * 68;

    // dense weights
    const float dw0 = lw[l64], dw1 = lw[64 + l64], dw2 = lw[128 + l64], dw3 = lw[192 + l64];

    float psp = 0.f, rr = 0.f;       // scan1 state
    float psp2 = 0.f, rr2 = 0.f;     // scan2 state (tid<128)

    float vbuf[8];
    #pragma unroll
    for (int k = 0; k < 8; ++k) vbuf[k] = up[(size_t)k * 16384];

    __syncthreads();   // ring zero + wl visible before first use

    #pragma unroll 1
    for (int rd = 0; rd < 13; ++rd) {
        const int t0 = rd * 8;
        const int cnt = (rd == 12) ? 4 : 8;

        // --- scan1: advance cnt steps (exact k2 math) ---
        float sreg[8];
        #pragma unroll
        for (int k = 0; k < 8; ++k) {
            if (k < cnt) {
                psp = a * psp + vbuf[k];
                const float vv = psp - rr;
                const float s = (vv >= 1.f) ? 1.f : 0.f;
                rr = a * (rr + s);
                sreg[k] = s;
            }
        }
        // --- prefetch next round's u1 (latency hides behind conv2/dense) ---
        #pragma unroll
        for (int k = 0; k < 8; ++k) {
            const int tt = t0 + 8 + k;
            if (tt < 100) vbuf[k] = up[(size_t)tt * 16384];
        }
        // --- publish spikes to ls1 ring ---
        #pragma unroll
        for (int k = 0; k < 8; ++k)
            if (k < cnt) ls1[k * 660 + woff] = sreg[k];
        __syncthreads();

        // --- conv2: slot sub (verbatim k3 body) ---
        if (sub < cnt) {
            const float* tb = ls1 + sub * 660 + i2 * 16;
            float acc[4] = {0.f, 0.f, 0.f, 0.f};
            #pragma unroll
            for (int cin = 0; cin < 4; ++cin) {
                #pragma unroll
                for (int e = 0; e < 4; ++e) {
                    const int C = cin * 160 + ((e & 1) * 5 + (e >> 1)) * 16;
                    float xr[16];
                    #pragma unroll
                    for (int b = 0; b < 4; ++b)
                        *(float4*)(xr + 4 * b) = *(const float4*)(tb + C + 4 * b);
                    float wv[4];
                    *(float4*)(wv) = *(const float4*)(wb + cin * 16 + e * 4);
                    #pragma unroll
                    for (int j = 0; j < 4; ++j) {
                        #pragma unroll
                        for (int f = 0; f < 4; ++f)
                            acc[j] += xr[2 * j + f + 3] * wv[f];
                    }
                }
            }
            *(float4*)(ls2 + sub * 132 + c2 * 16 + i2 * 4) =
                make_float4(acc[0], acc[1], acc[2], acc[3]);
        }
        __syncthreads();

        // --- scan2: thread = u2 neuron (tid<128), in-place u2 -> s2 ---
        if (tid < 128) {
            #pragma unroll
            for (int k = 0; k < 8; ++k) {
                if (k < cnt) {
                    const float u = ls2[k * 132 + tid];
                    psp2 = a * psp2 + u;
                    const float vv = psp2 - rr2;
                    const float s = (vv >= 1.f) ? 1.f : 0.f;
                    rr2 = a * (rr2 + s);
                    ls2[k * 132 + tid] = s;
                }
            }
        }
        __syncthreads();

        // --- dense: wave handles slots wave and wave+4 (exact k45 tree) ---
        #pragma unroll
        for (int h = 0; h < 2; ++h) {
            const int ss = wave + 4 * h;
            if (ss < cnt) {
                const float sa = ls2[ss * 132 + l64];
                const float sb = ls2[ss * 132 + 64 + l64];
                float a0 = sa * dw0 + sb * dw1;
                float a1 = sa * dw2 + sb * dw3;
                #pragma unroll
                for (int off = 32; off > 0; off >>= 1) {
                    a0 += __shfl_down(a0, off);
                    a1 += __shfl_down(a1, off);
                }
                if (l64 == 0) {
                    const int tt = t0 + ss;
                    out[n * 200 + tt * 2]     = a0;
                    out[n * 200 + tt * 2 + 1] = a1;
                }
            }
        }
        __syncthreads();   // protect ls1/ls2 reuse next round
    }
}

extern "C" void kernel_launch(void* const* d_in, const int* in_sizes, int n_in,
                              void* d_out, int out_size, void* d_ws, size_t ws_size,
                              hipStream_t stream) {
    const float* x   = (const float*)d_in[0];
    const float* w1  = (const float*)d_in[1];
    const float* w2  = (const float*)d_in[2];
    const float* lw  = (const float*)d_in[3];
    const float* wp1 = (const float*)d_in[4];
    const float* wp2 = (const float*)d_in[5];

    float* u1  = (float*)d_ws;           // 1,638,400 floats
    float* wl1 = u1 + 1638400;           //       512 floats
    float* wl2 = wl1 + 512;              //       544 floats
    float* out = (float*)d_out;          // (64,100,2)

    k0_fold<<<1, 128, 0, stream>>>(w1, w2, wp1, wp2, wl1, wl2);
    k1<<<6400, 64, 0, stream>>>(x, wl1, u1);
    kf<<<64, 256, 0, stream>>>(u1, wl2, lw, out);
}